// Round 6
// baseline (115.100 us; speedup 1.0000x reference)
//
#include <hip/hip_runtime.h>

// Shapes: B=256, N=P=32, OBS=96, ACT=32, DIN=DOUT=128, DF1=64, DF2=32
#define VAL_SZ  (256*32*32*32)
#define W_OFF   VAL_SZ
#define WP_OFF  (VAL_SZ + 256*32*32)

typedef short  bf16x8 __attribute__((ext_vector_type(8)));
typedef float  f32x4  __attribute__((ext_vector_type(4)));

#define MFMA(a, b, c) __builtin_amdgcn_mfma_f32_16x16x32_bf16(a, b, c, 0, 0, 0)

static __device__ __forceinline__ unsigned short f2bf(float f) {
    union { float f; unsigned u; } v; v.f = f;
    unsigned r = (v.u + 0x7FFF + ((v.u >> 16) & 1)) >> 16;
    return (unsigned short)r;
}
static __device__ __forceinline__ float bf2f(unsigned short u) {
    union { unsigned u; float f; } v; v.u = ((unsigned)u) << 16;
    return v.f;
}
static __device__ __forceinline__ float fast_tanh(float x) {
    x = fminf(fmaxf(x, -12.0f), 12.0f);
    float e = __expf(2.0f * x);
    return (e - 1.0f) / (e + 1.0f);
}

// A-frag (or row-major-B-frag) from bf16 LDS; stride in ushorts, multiple of 8.
static __device__ __forceinline__ bf16x8 afrag(const unsigned short* Mb, int stride,
                                               int row0, int kt) {
    int lane = threadIdx.x & 63;
    return *(const bf16x8*)(Mb + (row0 + (lane & 15)) * stride + kt * 32 + (lane >> 4) * 8);
}

// B-frag gathered from row-major fp32 global W[K][ldn], converted to bf16.
// Element: B[kt*32 + quad*8 + j][nt*16 + l16].
static __device__ __forceinline__ bf16x8 bfrag_gather(const float* __restrict__ W,
                                                      int ldn, int kt, int nt) {
    int lane = threadIdx.x & 63;
    int l16 = lane & 15, quad = lane >> 4;
    const float* p = W + (kt * 32 + quad * 8) * ldn + nt * 16 + l16;
    union { unsigned short u[8]; bf16x8 v; } o;
#pragma unroll
    for (int j = 0; j < 8; ++j) o.u[j] = f2bf(p[j * ldn]);
    return o.v;
}

// ---------------------------------------------------------------------------
// Single fused kernel. grid 256 x 1024 threads (16 waves), 8 barriers.
// LDS 64000 B, regions aliased over phases:
//  OA  @0      8704  oa [32x136]            -> NF[32x264] spans OA+TD (PE..PG)
//  TD  @8704   8704  delta [32x136]
//  OP  @17408  8704  op -> oap
//  QL  @26112  8704  q -> qp -> WPB[32x32 bf16] -> FP[32x66 f32]
//  KL  @34816  8704  k -> kp -> GP[32x67 f32]
//  VT  @43520  8192  vaT [128x32]
//  AVT @51712  8192  avpT [128x32]
//  SB1 @59904  2048  scores bf16 [a][j] -> weight bf16 [a][j]
//  SB2 @61952  2048  scores_p bf16 [p][n]
// ---------------------------------------------------------------------------
__global__ __launch_bounds__(1024) void critic_fused(
    const float* __restrict__ states, const float* __restrict__ policies,
    const float* __restrict__ actions, const float* __restrict__ states_p,
    const float* __restrict__ actions_p,
    const float* __restrict__ Wk, const float* __restrict__ Wq,
    const float* __restrict__ Wv, const float* __restrict__ Wkp,
    const float* __restrict__ Wqp, const float* __restrict__ Wvp,
    const float* __restrict__ Wf1, const float* __restrict__ Wf2,
    float* __restrict__ out)
{
    __shared__ __align__(16) unsigned char SM[64000];
    unsigned short* OA  = (unsigned short*)(SM + 0);
    unsigned short* TD  = (unsigned short*)(SM + 8704);
    unsigned short* NF  = (unsigned short*)(SM + 0);       // 32 x 264
    unsigned short* OP  = (unsigned short*)(SM + 17408);
    unsigned short* QL  = (unsigned short*)(SM + 26112);
    unsigned short* WPB = (unsigned short*)(SM + 26112);   // wp [n][p] bf16
    float*          FP  = (float*)(SM + 26112);            // F 32 x 66
    unsigned short* KL  = (unsigned short*)(SM + 34816);
    float*          GP  = (float*)(SM + 34816);            // G 32 x 67
    unsigned short* VT  = (unsigned short*)(SM + 43520);   // vaT 128 x 32
    unsigned short* AVT = (unsigned short*)(SM + 51712);   // avpT 128 x 32
    unsigned short* SB1 = (unsigned short*)(SM + 59904);   // 32 x 32
    unsigned short* SB2 = (unsigned short*)(SM + 61952);   // 32 x 32

    const int tid = threadIdx.x;
    const int b = blockIdx.x;
    const int lane = tid & 63, wv = tid >> 6;              // wv 0..15
    const int l16 = lane & 15, quad = lane >> 4;
    const float invN = 1.0f / 32.0f;
    const float scale = 0.08838834764831845f;              // 1/sqrt(128)
    const f32x4 Z = {0.f, 0.f, 0.f, 0.f};

    // ---- P0: load oa -> OA, op -> OP (bf16) ----
    {
        const float* st = states   + (size_t)b * 3072;
        const float* ac = actions  + (size_t)b * 1024;
        const float* po = policies + (size_t)b * 1024;
#pragma unroll
        for (int k = 0; k < 4; ++k) {
            int idx = tid + k * 1024;
            int n = idx >> 7, d = idx & 127;
            float sv, pv;
            if (d < 96) { sv = st[n * 96 + d]; pv = sv; }
            else        { sv = ac[n * 32 + d - 96]; pv = po[n * 32 + d - 96]; }
            OA[n * 136 + d] = f2bf(sv);
            OP[n * 136 + d] = f2bf(pv);
        }
    }
    __syncthreads();

    // ---- PA: wv0-7: va->VT, delta->TD ; wv8-15: q->QL, k->KL ----
    if (wv < 8) {
        int mt = wv & 1, ntA = wv >> 1, ntB = ntA + 4;
        f32x4 va0 = Z, va1 = Z, vp0 = Z, vp1 = Z;
#pragma unroll
        for (int kt = 0; kt < 4; ++kt) {
            bf16x8 aA = afrag(OA, 136, mt * 16, kt);
            bf16x8 aP = afrag(OP, 136, mt * 16, kt);
            bf16x8 b0 = bfrag_gather(Wv, 128, kt, ntA);
            bf16x8 b1 = bfrag_gather(Wv, 128, kt, ntB);
            va0 = MFMA(aA, b0, va0); va1 = MFMA(aA, b1, va1);
            vp0 = MFMA(aP, b0, vp0); vp1 = MFMA(aP, b1, vp1);
        }
#pragma unroll
        for (int r = 0; r < 4; ++r) {
            int row = mt * 16 + quad * 4 + r;
            float tva0 = fast_tanh(va0[r]), tvp0 = fast_tanh(vp0[r]);
            float tva1 = fast_tanh(va1[r]), tvp1 = fast_tanh(vp1[r]);
            VT[(ntA * 16 + l16) * 32 + row] = f2bf(tva0);
            VT[(ntB * 16 + l16) * 32 + row] = f2bf(tva1);
            TD[row * 136 + ntA * 16 + l16] = f2bf(tvp0 - tva0);
            TD[row * 136 + ntB * 16 + l16] = f2bf(tvp1 - tva1);
        }
    } else {
        int s = wv - 8;
        int mt = s & 1, pb2 = s >> 1;                      // 0..3
        bf16x8 afr[4];
#pragma unroll
        for (int kt = 0; kt < 4; ++kt) afr[kt] = afrag(OA, 136, mt * 16, kt);
#pragma unroll
        for (int m2 = 0; m2 < 2; ++m2) {
            const float* W = m2 ? Wk : Wq;
            unsigned short* dst = m2 ? KL : QL;
#pragma unroll
            for (int h = 0; h < 2; ++h) {
                int nt = pb2 + h * 4;
                f32x4 acc = Z;
#pragma unroll
                for (int kt = 0; kt < 4; ++kt)
                    acc = MFMA(afr[kt], bfrag_gather(W, 128, kt, nt), acc);
#pragma unroll
                for (int r = 0; r < 4; ++r)
                    dst[(mt * 16 + quad * 4 + r) * 136 + nt * 16 + l16] = f2bf(acc[r]);
            }
        }
    }
    __syncthreads();

    // ---- PB: wv0-7: G=delta@Wf1_top (regs); wv8-11: scores->SB1; wv12-15: oap->OP
    f32x4 gReg = Z;
    int gmt = 0, gnt = 0;
    if (wv < 8) {
        gmt = wv & 1; gnt = wv >> 1;                       // 8 tiles of 32x64
#pragma unroll
        for (int kt = 0; kt < 4; ++kt)
            gReg = MFMA(afrag(TD, 136, gmt * 16, kt), bfrag_gather(Wf1, 64, kt, gnt), gReg);
    } else if (wv < 12) {
        int s = wv - 8;
        int mt = s & 1, nt = s >> 1;
        f32x4 acc = Z;
#pragma unroll
        for (int kt = 0; kt < 4; ++kt)
            acc = MFMA(afrag(QL, 136, mt * 16, kt), afrag(KL, 136, nt * 16, kt), acc);
        // D[m=j][n=a]; store transposed -> SB1[a][j]
#pragma unroll
        for (int r = 0; r < 4; ++r)
            SB1[(nt * 16 + l16) * 32 + mt * 16 + quad * 4 + r] = f2bf(acc[r]);
    } else {
        const float* st = states_p  + (size_t)b * 3072;
        const float* ac = actions_p + (size_t)b * 1024;
        int t256 = tid - 768;
#pragma unroll
        for (int k = 0; k < 16; ++k) {
            int idx = t256 + k * 256;
            int n = idx >> 7, d = idx & 127;
            OP[n * 136 + d] = f2bf((d < 96) ? st[n * 96 + d] : ac[n * 32 + d - 96]);
        }
    }
    __syncthreads();

    // ---- PC: all waves: qp->QL, kp->KL, avp->AVT (1 tile each) ----
    {
        int mt = wv & 1, nt = wv >> 1;                     // nt 0..7
        bf16x8 ao[4], ap[4];
#pragma unroll
        for (int kt = 0; kt < 4; ++kt) {
            ao[kt] = afrag(OA, 136, mt * 16, kt);
            ap[kt] = afrag(OP, 136, mt * 16, kt);
        }
        f32x4 aq = Z, akp = Z, aav = Z;
#pragma unroll
        for (int kt = 0; kt < 4; ++kt) {
            aq  = MFMA(ao[kt], bfrag_gather(Wqp, 128, kt, nt), aq);
            akp = MFMA(ap[kt], bfrag_gather(Wkp, 128, kt, nt), akp);
            aav = MFMA(ap[kt], bfrag_gather(Wvp, 128, kt, nt), aav);
        }
#pragma unroll
        for (int r = 0; r < 4; ++r) {
            int row = mt * 16 + quad * 4 + r;
            QL[row * 136 + nt * 16 + l16] = f2bf(aq[r]);
            KL[row * 136 + nt * 16 + l16] = f2bf(akp[r]);
            AVT[(nt * 16 + l16) * 32 + row] = f2bf(fast_tanh(aav[r]));
        }
    }
    __syncthreads();

    // ---- PD: wv0-3: scores_p->SB2 ; wv8-15: weight softmax ----
    if (wv < 4) {
        int mt = wv & 1, nt = wv >> 1;
        f32x4 acc = Z;
#pragma unroll
        for (int kt = 0; kt < 4; ++kt)
            acc = MFMA(afrag(QL, 136, mt * 16, kt), afrag(KL, 136, nt * 16, kt), acc);
        // D[m=n][n'=p]; store transposed -> SB2[p][n]
#pragma unroll
        for (int r = 0; r < 4; ++r)
            SB2[(nt * 16 + l16) * 32 + mt * 16 + quad * 4 + r] = f2bf(acc[r]);
    } else if (wv >= 8) {
        int t512 = tid - 512;
#pragma unroll
        for (int rep = 0; rep < 2; ++rep) {
            int idx = t512 + rep * 512;
            int j = idx & 31, a = idx >> 5;
            float x = bf2f(SB1[a * 32 + j]) * scale;
            float m = x;
#pragma unroll
            for (int msk = 16; msk >= 1; msk >>= 1) m = fmaxf(m, __shfl_xor(m, msk));
            float e = __expf(x - m);
            float s = e;
#pragma unroll
            for (int msk = 16; msk >= 1; msk >>= 1) s += __shfl_xor(s, msk);
            float w = e / s;
            out[W_OFF + (size_t)b * 1024 + a * 32 + j] = w;
            SB1[a * 32 + j] = f2bf(w);
        }
    }
    __syncthreads();

    // ---- PE: wv0-7: wp softmax (SB2->WPB + export); wv8-15: S_acc -> NF ----
    if (wv < 8) {
#pragma unroll
        for (int rep = 0; rep < 2; ++rep) {
            int idx = tid + rep * 512;
            int n = idx & 31, p = idx >> 5;
            float x = bf2f(SB2[p * 32 + n]) * scale;
            float m = x;
#pragma unroll
            for (int msk = 16; msk >= 1; msk >>= 1) m = fmaxf(m, __shfl_xor(m, msk));
            float e = __expf(x - m);
            float s = e;
#pragma unroll
            for (int msk = 16; msk >= 1; msk >>= 1) s += __shfl_xor(s, msk);
            float w2 = e / s;
            out[WP_OFF + (size_t)b * 1024 + n * 32 + p] = w2;
            WPB[n * 32 + p] = f2bf(w2);
        }
    } else {
        int s = wv - 8;
        int mt = s & 1, nt0 = s >> 1, nt1 = nt0 + 4;
        bf16x8 aw = afrag(SB1, 32, mt * 16, 0);
        f32x4 s0 = MFMA(aw, afrag(VT, 32, nt0 * 16, 0), Z);
        f32x4 s1 = MFMA(aw, afrag(VT, 32, nt1 * 16, 0), Z);
#pragma unroll
        for (int r = 0; r < 4; ++r) {
            int row = mt * 16 + quad * 4 + r;
            NF[row * 264 + nt0 * 16 + l16] = f2bf(s0[r] * invN);
            NF[row * 264 + nt1 * 16 + l16] = f2bf(s1[r] * invN);
        }
    }
    __syncthreads();

    // ---- PF: all waves: wavp = wp@avp -> NF[:,128:256] ----
    {
        int mt = wv & 1, nt = wv >> 1;
        f32x4 acc = MFMA(afrag(WPB, 32, mt * 16, 0), afrag(AVT, 32, nt * 16, 0), Z);
#pragma unroll
        for (int r = 0; r < 4; ++r) {
            int row = mt * 16 + quad * 4 + r;
            NF[row * 264 + 128 + nt * 16 + l16] = f2bf(acc[r] * invN);
        }
    }
    __syncthreads();

    // ---- PG: wv0-7: F = NF@Wf1 (K=256) -> FP; park gReg -> GP ----
    if (wv < 8) {
        int mt = wv & 1, nt = wv >> 1;                     // nt 0..3
        f32x4 f = Z;
#pragma unroll
        for (int kt = 0; kt < 8; ++kt)
            f = MFMA(afrag(NF, 264, mt * 16, kt), bfrag_gather(Wf1, 64, kt, nt), f);
#pragma unroll
        for (int r = 0; r < 4; ++r) {
            FP[(mt * 16 + quad * 4 + r) * 66 + nt * 16 + l16] = f[r];
            GP[(gmt * 16 + quad * 4 + r) * 67 + gnt * 16 + l16] = gReg[r];
        }
    }
    __syncthreads();

    // ---- Epilogue: value tiles via MFMA; h built in-register (A-frag order)
    {
        bf16x8 bw[2][2];
#pragma unroll
        for (int kt = 0; kt < 2; ++kt)
#pragma unroll
            for (int nt = 0; nt < 2; ++nt)
                bw[kt][nt] = bfrag_gather(Wf2, 32, kt, nt);

#pragma unroll
        for (int t4 = 0; t4 < 4; ++t4) {
            int tile = wv + t4 * 16;                       // 0..63
            int m0 = tile * 16;
            int a = m0 >> 5;
            int i = (m0 & 31) + l16;
            float w = bf2f(SB1[a * 32 + i]) * invN;
            const float* Fa = FP + a * 66;
            const float* Gi = GP + i * 67;
            f32x4 acc0 = Z, acc1 = Z;
#pragma unroll
            for (int kt = 0; kt < 2; ++kt) {
                union { unsigned short u[8]; bf16x8 v; } h;
                int dbase = kt * 32 + quad * 8;
#pragma unroll
                for (int j = 0; j < 8; ++j) {
                    float z = fmaf(w, Gi[dbase + j], Fa[dbase + j]);
                    z = fmaxf(z, 0.01f * z);               // leaky_relu
                    h.u[j] = f2bf(z);
                }
                acc0 = MFMA(h.v, bw[kt][0], acc0);
                acc1 = MFMA(h.v, bw[kt][1], acc1);
            }
            float* base = out + (size_t)b * 32768 + (size_t)m0 * 32;
#pragma unroll
            for (int r = 0; r < 4; ++r) {
                int row = quad * 4 + r;
                base[row * 32 + l16]      = acc0[r];
                base[row * 32 + 16 + l16] = acc1[r];
            }
        }
    }
}

// ---------------------------------------------------------------------------
extern "C" void kernel_launch(void* const* d_in, const int* in_sizes, int n_in,
                              void* d_out, int out_size, void* d_ws, size_t ws_size,
                              hipStream_t stream)
{
    const float* states    = (const float*)d_in[0];
    const float* policies  = (const float*)d_in[1];
    const float* actions   = (const float*)d_in[2];
    const float* states_p  = (const float*)d_in[3];
    const float* actions_p = (const float*)d_in[4];
    const float* Wk        = (const float*)d_in[5];
    const float* Wq        = (const float*)d_in[6];
    const float* Wv        = (const float*)d_in[7];
    const float* Wkp       = (const float*)d_in[8];
    const float* Wqp       = (const float*)d_in[9];
    const float* Wvp       = (const float*)d_in[10];
    const float* Wf1       = (const float*)d_in[11];
    const float* Wf2       = (const float*)d_in[12];
    float* out = (float*)d_out;

    critic_fused<<<256, 1024, 0, stream>>>(states, policies, actions,
                                           states_p, actions_p,
                                           Wk, Wq, Wv, Wkp, Wqp, Wvp,
                                           Wf1, Wf2, out);
}

// Round 7
// 109.019 us; speedup vs baseline: 1.0558x; 1.0558x over previous
//
#include <hip/hip_runtime.h>

// Shapes: B=256, N=P=32, OBS=96, ACT=32, DIN=DOUT=128, DF1=64, DF2=32
#define VAL_SZ  (256*32*32*32)
#define W_OFF   VAL_SZ
#define WP_OFF  (VAL_SZ + 256*32*32)

// packed bf16 weights in ws (ushort offsets); B-frag order
#define PK_WV   0
#define PK_WVP  16384
#define PK_WQ   32768        // pre-scaled by 1/sqrt(128)
#define PK_WK   49152
#define PK_WQP  65536        // pre-scaled by 1/sqrt(128)
#define PK_WKP  81920
#define PK_WF1  98304        // 256x64 (kt 0..7, nt 0..3)
#define PK_WF2  114688       // 64x32  (kt 0..1, nt 0..1)

typedef short  bf16x8 __attribute__((ext_vector_type(8)));
typedef float  f32x4  __attribute__((ext_vector_type(4)));

#define MFMA(a, b, c) __builtin_amdgcn_mfma_f32_16x16x32_bf16(a, b, c, 0, 0, 0)

static __device__ __forceinline__ unsigned short f2bf(float f) {
    union { float f; unsigned u; } v; v.f = f;
    unsigned r = (v.u + 0x7FFF + ((v.u >> 16) & 1)) >> 16;
    return (unsigned short)r;
}
static __device__ __forceinline__ float bf2f(unsigned short u) {
    union { unsigned u; float f; } v; v.u = ((unsigned)u) << 16;
    return v.f;
}
static __device__ __forceinline__ float fast_tanh(float x) {
    x = fminf(fmaxf(x, -12.0f), 12.0f);
    float e = __expf(2.0f * x);
    return (e - 1.0f) / (e + 1.0f);
}

// A-frag (or row-major-B-frag) from bf16 LDS; stride in ushorts, multiple of 8.
static __device__ __forceinline__ bf16x8 afrag(const unsigned short* Mb, int stride,
                                               int row0, int kt) {
    int lane = threadIdx.x & 63;
    return *(const bf16x8*)(Mb + (row0 + (lane & 15)) * stride + kt * 32 + (lane >> 4) * 8);
}

// B-frag from packed global weights (single 16B load, L2-resident)
static __device__ __forceinline__ bf16x8 bfrag_pk(const unsigned short* base, int NT,
                                                  int kt, int nt) {
    int lane = threadIdx.x & 63;
    return *(const bf16x8*)(base + (((kt * NT + nt) * 64) + lane) * 8);
}

// ---------------------------------------------------------------------------
// Kernel 0 (lite): pure transpose/convert pack of all 8 weight matrices into
// bf16 B-fragment order. No GEMM. 14592 lane-slots -> 57 blocks x 256.
// Element: B[kt*32 + quad*8 + j][nt*16 + l16] at pk[OFF+((kt*NT+nt)*64+lane)*8+j]
// ---------------------------------------------------------------------------
__global__ __launch_bounds__(256) void pack_lite(
    const float* __restrict__ Wk, const float* __restrict__ Wq,
    const float* __restrict__ Wv, const float* __restrict__ Wkp,
    const float* __restrict__ Wqp, const float* __restrict__ Wvp,
    const float* __restrict__ Wf1, const float* __restrict__ Wf2,
    unsigned short* __restrict__ pk)
{
    const float scale = 0.08838834764831845f;     // 1/sqrt(128)
    int gid = blockIdx.x * 256 + threadIdx.x;
    if (gid >= 14592) return;

    const float* W; int off, NT, ldn; float s = 1.0f;
    int r;
    if (gid < 12288) {                 // six 128x128 matrices
        int mat = gid >> 11;           // 0..5
        r = gid & 2047;
        NT = 8; ldn = 128;
        switch (mat) {
            case 0: W = Wv;  off = PK_WV;  break;
            case 1: W = Wvp; off = PK_WVP; break;
            case 2: W = Wq;  off = PK_WQ;  s = scale; break;
            case 3: W = Wk;  off = PK_WK;  break;
            case 4: W = Wqp; off = PK_WQP; s = scale; break;
            default: W = Wkp; off = PK_WKP; break;
        }
    } else if (gid < 14336) {          // Wf1 256x64
        r = gid - 12288; W = Wf1; off = PK_WF1; NT = 4; ldn = 64;
    } else {                           // Wf2 64x32
        r = gid - 14336; W = Wf2; off = PK_WF2; NT = 2; ldn = 32;
    }
    int lane = r & 63;
    int l16 = lane & 15, quad = lane >> 4;
    int ktnt = r >> 6;
    int nt = ktnt % NT, kt = ktnt / NT;
    int n = nt * 16 + l16;
    int kb = kt * 32 + quad * 8;
    union { unsigned short u[8]; bf16x8 v; } o;
#pragma unroll
    for (int j = 0; j < 8; ++j) o.u[j] = f2bf(W[(kb + j) * ldn + n] * s);
    *(bf16x8*)(pk + off + (ktnt * 64 + lane) * 8) = o.v;
}

// ---------------------------------------------------------------------------
// Kernel A: fused per-batch forward. grid 256 x 1024 threads (16 waves),
// 8 barriers, wave-specialized. LDS 64000 B, regions aliased over phases:
//  OA  @0      8704  oa [32x136]            -> NF[32x264] spans OA+TD (PE..PG)
//  TD  @8704   8704  delta [32x136]
//  OP  @17408  8704  op -> oap
//  QL  @26112  8704  q -> qp -> WPB[32x32 bf16] -> FP[32x66 f32]
//  KL  @34816  8704  k -> kp -> GP[32x67 f32]
//  VT  @43520  8192  vaT [128x32]
//  AVT @51712  8192  avpT [128x32]
//  SB1 @59904  2048  scores bf16 [a][j] -> weight bf16 [a][j]
//  SB2 @61952  2048  scores_p bf16 [p][n]
// ---------------------------------------------------------------------------
__global__ __launch_bounds__(1024) void critic_fused(
    const float* __restrict__ states, const float* __restrict__ policies,
    const float* __restrict__ actions, const float* __restrict__ states_p,
    const float* __restrict__ actions_p,
    const unsigned short* __restrict__ pk, float* __restrict__ out)
{
    __shared__ __align__(16) unsigned char SM[64000];
    unsigned short* OA  = (unsigned short*)(SM + 0);
    unsigned short* TD  = (unsigned short*)(SM + 8704);
    unsigned short* NF  = (unsigned short*)(SM + 0);       // 32 x 264
    unsigned short* OP  = (unsigned short*)(SM + 17408);
    unsigned short* QL  = (unsigned short*)(SM + 26112);
    unsigned short* WPB = (unsigned short*)(SM + 26112);   // wp [n][p] bf16
    float*          FP  = (float*)(SM + 26112);            // F 32 x 66
    unsigned short* KL  = (unsigned short*)(SM + 34816);
    float*          GP  = (float*)(SM + 34816);            // G 32 x 67
    unsigned short* VT  = (unsigned short*)(SM + 43520);   // vaT 128 x 32
    unsigned short* AVT = (unsigned short*)(SM + 51712);   // avpT 128 x 32
    unsigned short* SB1 = (unsigned short*)(SM + 59904);   // 32 x 32
    unsigned short* SB2 = (unsigned short*)(SM + 61952);   // 32 x 32

    const int tid = threadIdx.x;
    const int b = blockIdx.x;
    const int lane = tid & 63, wv = tid >> 6;              // wv 0..15
    const int l16 = lane & 15, quad = lane >> 4;
    const float invN = 1.0f / 32.0f;
    const f32x4 Z = {0.f, 0.f, 0.f, 0.f};

    // ---- P0: load oa -> OA, op -> OP (bf16) ----
    {
        const float* st = states   + (size_t)b * 3072;
        const float* ac = actions  + (size_t)b * 1024;
        const float* po = policies + (size_t)b * 1024;
#pragma unroll
        for (int k = 0; k < 4; ++k) {
            int idx = tid + k * 1024;
            int n = idx >> 7, d = idx & 127;
            float sv, pv;
            if (d < 96) { sv = st[n * 96 + d]; pv = sv; }
            else        { sv = ac[n * 32 + d - 96]; pv = po[n * 32 + d - 96]; }
            OA[n * 136 + d] = f2bf(sv);
            OP[n * 136 + d] = f2bf(pv);
        }
    }
    __syncthreads();

    // ---- PA: wv0-7: va->VT, delta->TD ; wv8-15: q->QL, k->KL ----
    if (wv < 8) {
        int mt = wv & 1, ntA = wv >> 1, ntB = ntA + 4;
        f32x4 va0 = Z, va1 = Z, vp0 = Z, vp1 = Z;
#pragma unroll
        for (int kt = 0; kt < 4; ++kt) {
            bf16x8 aA = afrag(OA, 136, mt * 16, kt);
            bf16x8 aP = afrag(OP, 136, mt * 16, kt);
            bf16x8 b0 = bfrag_pk(pk + PK_WV, 8, kt, ntA);
            bf16x8 b1 = bfrag_pk(pk + PK_WV, 8, kt, ntB);
            va0 = MFMA(aA, b0, va0); va1 = MFMA(aA, b1, va1);
            vp0 = MFMA(aP, b0, vp0); vp1 = MFMA(aP, b1, vp1);
        }
#pragma unroll
        for (int r = 0; r < 4; ++r) {
            int row = mt * 16 + quad * 4 + r;
            float tva0 = fast_tanh(va0[r]), tvp0 = fast_tanh(vp0[r]);
            float tva1 = fast_tanh(va1[r]), tvp1 = fast_tanh(vp1[r]);
            VT[(ntA * 16 + l16) * 32 + row] = f2bf(tva0);
            VT[(ntB * 16 + l16) * 32 + row] = f2bf(tva1);
            TD[row * 136 + ntA * 16 + l16] = f2bf(tvp0 - tva0);
            TD[row * 136 + ntB * 16 + l16] = f2bf(tvp1 - tva1);
        }
    } else {
        int s = wv - 8;
        int mt = s & 1, pb2 = s >> 1;                      // 0..3
        bf16x8 afr[4];
#pragma unroll
        for (int kt = 0; kt < 4; ++kt) afr[kt] = afrag(OA, 136, mt * 16, kt);
#pragma unroll
        for (int m2 = 0; m2 < 2; ++m2) {
            const unsigned short* pkM = pk + (m2 ? PK_WK : PK_WQ);
            unsigned short* dst = m2 ? KL : QL;
#pragma unroll
            for (int h = 0; h < 2; ++h) {
                int nt = pb2 + h * 4;
                f32x4 acc = Z;
#pragma unroll
                for (int kt = 0; kt < 4; ++kt)
                    acc = MFMA(afr[kt], bfrag_pk(pkM, 8, kt, nt), acc);
#pragma unroll
                for (int r = 0; r < 4; ++r)
                    dst[(mt * 16 + quad * 4 + r) * 136 + nt * 16 + l16] = f2bf(acc[r]);
            }
        }
    }
    __syncthreads();

    // ---- PB: wv0-7: G=delta@Wf1_top (regs); wv8-11: scores->SB1; wv12-15: oap->OP
    f32x4 gReg = Z;
    int gmt = 0, gnt = 0;
    if (wv < 8) {
        gmt = wv & 1; gnt = wv >> 1;                       // 8 tiles of 32x64
#pragma unroll
        for (int kt = 0; kt < 4; ++kt)
            gReg = MFMA(afrag(TD, 136, gmt * 16, kt), bfrag_pk(pk + PK_WF1, 4, kt, gnt), gReg);
    } else if (wv < 12) {
        int s = wv - 8;
        int mt = s & 1, nt = s >> 1;
        f32x4 acc = Z;
#pragma unroll
        for (int kt = 0; kt < 4; ++kt)
            acc = MFMA(afrag(QL, 136, mt * 16, kt), afrag(KL, 136, nt * 16, kt), acc);
        // D[m=j][n=a]; store transposed -> SB1[a][j]
#pragma unroll
        for (int r = 0; r < 4; ++r)
            SB1[(nt * 16 + l16) * 32 + mt * 16 + quad * 4 + r] = f2bf(acc[r]);
    } else {
        const float* st = states_p  + (size_t)b * 3072;
        const float* ac = actions_p + (size_t)b * 1024;
        int t256 = tid - 768;
#pragma unroll
        for (int k = 0; k < 16; ++k) {
            int idx = t256 + k * 256;
            int n = idx >> 7, d = idx & 127;
            OP[n * 136 + d] = f2bf((d < 96) ? st[n * 96 + d] : ac[n * 32 + d - 96]);
        }
    }
    __syncthreads();

    // ---- PC: all waves: qp->QL, kp->KL, avp->AVT (1 tile each) ----
    {
        int mt = wv & 1, nt = wv >> 1;                     // nt 0..7
        bf16x8 ao[4], ap[4];
#pragma unroll
        for (int kt = 0; kt < 4; ++kt) {
            ao[kt] = afrag(OA, 136, mt * 16, kt);
            ap[kt] = afrag(OP, 136, mt * 16, kt);
        }
        f32x4 aq = Z, akp = Z, aav = Z;
#pragma unroll
        for (int kt = 0; kt < 4; ++kt) {
            aq  = MFMA(ao[kt], bfrag_pk(pk + PK_WQP, 8, kt, nt), aq);
            akp = MFMA(ap[kt], bfrag_pk(pk + PK_WKP, 8, kt, nt), akp);
            aav = MFMA(ap[kt], bfrag_pk(pk + PK_WVP, 8, kt, nt), aav);
        }
#pragma unroll
        for (int r = 0; r < 4; ++r) {
            int row = mt * 16 + quad * 4 + r;
            QL[row * 136 + nt * 16 + l16] = f2bf(aq[r]);
            KL[row * 136 + nt * 16 + l16] = f2bf(akp[r]);
            AVT[(nt * 16 + l16) * 32 + row] = f2bf(fast_tanh(aav[r]));
        }
    }
    __syncthreads();

    // ---- PD: wv0-3: scores_p->SB2 ; wv8-15: weight softmax ----
    if (wv < 4) {
        int mt = wv & 1, nt = wv >> 1;
        f32x4 acc = Z;
#pragma unroll
        for (int kt = 0; kt < 4; ++kt)
            acc = MFMA(afrag(QL, 136, mt * 16, kt), afrag(KL, 136, nt * 16, kt), acc);
        // D[m=n][n'=p]; store transposed -> SB2[p][n]
#pragma unroll
        for (int r = 0; r < 4; ++r)
            SB2[(nt * 16 + l16) * 32 + mt * 16 + quad * 4 + r] = f2bf(acc[r]);
    } else if (wv >= 8) {
        int t512 = tid - 512;
#pragma unroll
        for (int rep = 0; rep < 2; ++rep) {
            int idx = t512 + rep * 512;
            int j = idx & 31, a = idx >> 5;
            float x = bf2f(SB1[a * 32 + j]);               // scale pre-folded
            float m = x;
#pragma unroll
            for (int msk = 16; msk >= 1; msk >>= 1) m = fmaxf(m, __shfl_xor(m, msk));
            float e = __expf(x - m);
            float s = e;
#pragma unroll
            for (int msk = 16; msk >= 1; msk >>= 1) s += __shfl_xor(s, msk);
            float w = e / s;
            out[W_OFF + (size_t)b * 1024 + a * 32 + j] = w;
            SB1[a * 32 + j] = f2bf(w);
        }
    }
    __syncthreads();

    // ---- PE: wv0-7: wp softmax (SB2->WPB + export); wv8-15: S_acc -> NF ----
    if (wv < 8) {
#pragma unroll
        for (int rep = 0; rep < 2; ++rep) {
            int idx = tid + rep * 512;
            int n = idx & 31, p = idx >> 5;
            float x = bf2f(SB2[p * 32 + n]);               // scale pre-folded
            float m = x;
#pragma unroll
            for (int msk = 16; msk >= 1; msk >>= 1) m = fmaxf(m, __shfl_xor(m, msk));
            float e = __expf(x - m);
            float s = e;
#pragma unroll
            for (int msk = 16; msk >= 1; msk >>= 1) s += __shfl_xor(s, msk);
            float w2 = e / s;
            out[WP_OFF + (size_t)b * 1024 + n * 32 + p] = w2;
            WPB[n * 32 + p] = f2bf(w2);
        }
    } else {
        int s = wv - 8;
        int mt = s & 1, nt0 = s >> 1, nt1 = nt0 + 4;
        bf16x8 aw = afrag(SB1, 32, mt * 16, 0);
        f32x4 s0 = MFMA(aw, afrag(VT, 32, nt0 * 16, 0), Z);
        f32x4 s1 = MFMA(aw, afrag(VT, 32, nt1 * 16, 0), Z);
#pragma unroll
        for (int r = 0; r < 4; ++r) {
            int row = mt * 16 + quad * 4 + r;
            NF[row * 264 + nt0 * 16 + l16] = f2bf(s0[r] * invN);
            NF[row * 264 + nt1 * 16 + l16] = f2bf(s1[r] * invN);
        }
    }
    __syncthreads();

    // ---- PF: all waves: wavp = wp@avp -> NF[:,128:256] ----
    {
        int mt = wv & 1, nt = wv >> 1;
        f32x4 acc = MFMA(afrag(WPB, 32, mt * 16, 0), afrag(AVT, 32, nt * 16, 0), Z);
#pragma unroll
        for (int r = 0; r < 4; ++r) {
            int row = mt * 16 + quad * 4 + r;
            NF[row * 264 + 128 + nt * 16 + l16] = f2bf(acc[r] * invN);
        }
    }
    __syncthreads();

    // ---- PG: wv0-7: F = NF@Wf1 (K=256) -> FP; park gReg -> GP ----
    if (wv < 8) {
        int mt = wv & 1, nt = wv >> 1;                     // nt 0..3
        f32x4 f = Z;
#pragma unroll
        for (int kt = 0; kt < 8; ++kt)
            f = MFMA(afrag(NF, 264, mt * 16, kt), bfrag_pk(pk + PK_WF1, 4, kt, nt), f);
#pragma unroll
        for (int r = 0; r < 4; ++r) {
            FP[(mt * 16 + quad * 4 + r) * 66 + nt * 16 + l16] = f[r];
            GP[(gmt * 16 + quad * 4 + r) * 67 + gnt * 16 + l16] = gReg[r];
        }
    }
    __syncthreads();

    // ---- Epilogue: value tiles via MFMA; h built in-register (A-frag order)
    {
        bf16x8 bw[2][2];
#pragma unroll
        for (int kt = 0; kt < 2; ++kt)
#pragma unroll
            for (int nt = 0; nt < 2; ++nt)
                bw[kt][nt] = bfrag_pk(pk + PK_WF2, 2, kt, nt);

#pragma unroll
        for (int t4 = 0; t4 < 4; ++t4) {
            int tile = wv + t4 * 16;                       // 0..63
            int m0 = tile * 16;
            int a = m0 >> 5;
            int i = (m0 & 31) + l16;
            float w = bf2f(SB1[a * 32 + i]) * invN;
            const float* Fa = FP + a * 66;
            const float* Gi = GP + i * 67;
            f32x4 acc0 = Z, acc1 = Z;
#pragma unroll
            for (int kt = 0; kt < 2; ++kt) {
                union { unsigned short u[8]; bf16x8 v; } h;
                int dbase = kt * 32 + quad * 8;
#pragma unroll
                for (int j = 0; j < 8; ++j) {
                    float z = fmaf(w, Gi[dbase + j], Fa[dbase + j]);
                    z = fmaxf(z, 0.01f * z);               // leaky_relu
                    h.u[j] = f2bf(z);
                }
                acc0 = MFMA(h.v, bw[kt][0], acc0);
                acc1 = MFMA(h.v, bw[kt][1], acc1);
            }
            float* base = out + (size_t)b * 32768 + (size_t)m0 * 32;
#pragma unroll
            for (int r = 0; r < 4; ++r) {
                int row = quad * 4 + r;
                base[row * 32 + l16]      = acc0[r];
                base[row * 32 + 16 + l16] = acc1[r];
            }
        }
    }
}

// ---------------------------------------------------------------------------
extern "C" void kernel_launch(void* const* d_in, const int* in_sizes, int n_in,
                              void* d_out, int out_size, void* d_ws, size_t ws_size,
                              hipStream_t stream)
{
    const float* states    = (const float*)d_in[0];
    const float* policies  = (const float*)d_in[1];
    const float* actions   = (const float*)d_in[2];
    const float* states_p  = (const float*)d_in[3];
    const float* actions_p = (const float*)d_in[4];
    const float* Wk        = (const float*)d_in[5];
    const float* Wq        = (const float*)d_in[6];
    const float* Wv        = (const float*)d_in[7];
    const float* Wkp       = (const float*)d_in[8];
    const float* Wqp       = (const float*)d_in[9];
    const float* Wvp       = (const float*)d_in[10];
    const float* Wf1       = (const float*)d_in[11];
    const float* Wf2       = (const float*)d_in[12];
    float* out = (float*)d_out;
    unsigned short* pk = (unsigned short*)d_ws;

    pack_lite<<<57, 256, 0, stream>>>(Wk, Wq, Wv, Wkp, Wqp, Wvp, Wf1, Wf2, pk);
    critic_fused<<<256, 1024, 0, stream>>>(states, policies, actions,
                                           states_p, actions_p, pk, out);
}